// Round 11
// baseline (129.407 us; speedup 1.0000x reference)
//
#include <hip/hip_runtime.h>
#include <hip/hip_bf16.h>

// GCLSTM with H=C=None collapses to: gates from x@Wx only (conv = bconv const),
// forget gate dead, graph unused.
//   h1 = sig(zo)*tanh(sig(zi)*tanh(zc)),  z = x@Wx1[:,{i,c,o}] + bias
//   h2 = same with Wx2; out = relu(h2)@Wl + bl
//
// R11 vs R10 (R6..R10 all 129-135; R9's -2.8us from tiny pipe savings =>
// per-wave latency chains dominate; biggest: 4 k-stages x ~250cyc L2 stall
// for B-frags, re-paid per 16-node tile):
//  - TWO adjacent tiles per wave: B-frags shared (L2 B traffic halved to
//    150MB), each k-stage covers its load latency with 20 MFMAs not 10,
//    wave count 6252 -> 3125 (half the per-wave serial tails).
//  - GEMM1 double-buffered stage loads; gates per tile into separate LDS
//    regions; GEMM2+epilogue per tile sequential (sP reused, same-wave
//    lgkmcnt ordering). Unified-file audit: ~235 < 256 regs at (256,2).
//  - numerics identical to R10 (absmax 4.88e-4 expected unchanged).

#define NODES 100000
#define NTILES 6250
#define NJOBS 3125   // 2 tiles per wave-job

typedef float v4f   __attribute__((ext_vector_type(4)));
typedef float fragC __attribute__((ext_vector_type(4)));
typedef short frag8 __attribute__((ext_vector_type(8)));

// ws byte offsets
#define OFF_B1H 0       // 40 frags * 1024 B
#define OFF_B2H 40960   // 8 frags * 1024 B
#define OFF_PB1 49152   // 160 f32 packed-col biases (layer1)
#define OFF_PB2 49792   // 64 f32 packed-col biases (layer2)

__device__ __forceinline__ unsigned short f2bf(float f) {
  unsigned int u = __float_as_uint(f);
  u += 0x7fffu + ((u >> 16) & 1u);  // RNE
  return (unsigned short)(u >> 16);
}
__device__ __forceinline__ float fsig(float z) {
  float t = __builtin_amdgcn_exp2f(z * -1.44269504088896f);
  return __builtin_amdgcn_rcpf(1.0f + t);
}
__device__ __forceinline__ float ftanh(float z) {
  float t = __builtin_amdgcn_exp2f(z * 2.88539008177793f);
  return 1.0f - 2.0f * __builtin_amdgcn_rcpf(t + 1.0f);
}

union bfu { __hip_bfloat162 h; unsigned int u; };

__device__ __forceinline__ frag8 cvt8hi(const float* v) {
  frag8 hi;
#pragma unroll
  for (int p = 0; p < 4; ++p) {
    bfu c; c.h = __float22bfloat162_rn(make_float2(v[2 * p], v[2 * p + 1]));
    hi[2 * p]     = (short)(c.u & 0xffffu);
    hi[2 * p + 1] = (short)(c.u >> 16);
  }
  return hi;
}
__device__ __forceinline__ void cvt8(const float* v, frag8& hi, frag8& lo) {
  float lof[8];
#pragma unroll
  for (int p = 0; p < 4; ++p) {
    bfu c; c.h = __float22bfloat162_rn(make_float2(v[2 * p], v[2 * p + 1]));
    hi[2 * p]     = (short)(c.u & 0xffffu);
    hi[2 * p + 1] = (short)(c.u >> 16);
    lof[2 * p]     = v[2 * p]     - __uint_as_float((c.u & 0xffffu) << 16);
    lof[2 * p + 1] = v[2 * p + 1] - __uint_as_float(c.u & 0xffff0000u);
  }
#pragma unroll
  for (int p = 0; p < 4; ++p) {
    bfu c; c.h = __float22bfloat162_rn(make_float2(lof[2 * p], lof[2 * p + 1]));
    lo[2 * p]     = (short)(c.u & 0xffffu);
    lo[2 * p + 1] = (short)(c.u >> 16);
  }
}

// B1 packed-col: col = 16t+m.  t<=8: g=t%3, c=16*(t/3)+m.
// t==9: m<6 -> c=48+m/3, g=m%3; else pad.  g {i,c,o} -> Wx1 col {0,2,3}.
// B2 packed-col: col = 16t+m.  t<=2: g=t, c=m.
// t==3: m<12 -> c=16+m/3, g=m%3; else pad.  g -> Wx2 col {0,2,3}.
__global__ void pack_weights(const float* __restrict__ Wx1, const float* __restrict__ bx1,
                             const float* __restrict__ bconv1,
                             const float* __restrict__ Wx2, const float* __restrict__ bx2,
                             const float* __restrict__ bconv2,
                             unsigned char* __restrict__ ws) {
  const int tid = blockIdx.x * blockDim.x + threadIdx.x;
  const int stride = gridDim.x * blockDim.x;
  unsigned short* B1H = (unsigned short*)(ws + OFF_B1H);
  unsigned short* B2H = (unsigned short*)(ws + OFF_B2H);
  float* PB1 = (float*)(ws + OFF_PB1);
  float* PB2 = (float*)(ws + OFF_PB2);

  for (int idx = tid; idx < 20480; idx += stride) {
    int j = idx & 7, lane = (idx >> 3) & 63, ft = idx >> 9;  // ft = s*10+t
    int s = ft / 10, t = ft % 10;
    int k = 32 * s + ((lane >> 4) << 3) + j;
    int m = lane & 15;
    int c = -1, g = 0;
    if (t <= 8) { g = t % 3; c = 16 * (t / 3) + m; }
    else if (m < 6) { c = 48 + m / 3; g = m % 3; }
    float val = 0.f;
    if (c >= 0) {
      int gs = (g == 0) ? 0 : (g == 1) ? 2 : 3;
      val = Wx1[k * 200 + gs * 50 + c];
    }
    B1H[idx] = f2bf(val);
  }
  for (int idx = tid; idx < 4096; idx += stride) {
    int j = idx & 7, lane = (idx >> 3) & 63, ft = idx >> 9;  // ft = s*4+t
    int s = ft >> 2, t = ft & 3;
    int k = 32 * s + ((lane >> 4) << 3) + j;
    int m = lane & 15;
    int c = -1, g = 0;
    if (t <= 2) { g = t; c = m; }
    else if (m < 12) { c = 16 + m / 3; g = m % 3; }
    float val = 0.f;
    if (c >= 0 && k < 50) {
      int gs = (g == 0) ? 0 : (g == 1) ? 2 : 3;
      val = Wx2[k * 80 + gs * 20 + c];
    }
    B2H[idx] = f2bf(val);
  }
  for (int idx = tid; idx < 160; idx += stride) {
    int t = idx >> 4, m = idx & 15;
    int c = -1, g = 0;
    if (t <= 8) { g = t % 3; c = 16 * (t / 3) + m; }
    else if (m < 6) { c = 48 + m / 3; g = m % 3; }
    float v = 0.f;
    if (c >= 0) {
      int gs = (g == 0) ? 0 : (g == 1) ? 2 : 3;
      v = bx1[gs * 50 + c] + bconv1[gs * 50 + c];
    }
    PB1[idx] = v;
  }
  for (int idx = tid; idx < 64; idx += stride) {
    int t = idx >> 4, m = idx & 15;
    int c = -1, g = 0;
    if (t <= 2) { g = t; c = m; }
    else if (m < 12) { c = 16 + m / 3; g = m % 3; }
    float v = 0.f;
    if (c >= 0) {
      int gs = (g == 0) ? 0 : (g == 1) ? 2 : 3;
      v = bx2[gs * 20 + c] + bconv2[gs * 20 + c];
    }
    PB2[idx] = v;
  }
}

__global__ __launch_bounds__(256, 2) void gclstm_main(
    const float* __restrict__ x, const unsigned char* __restrict__ wsb,
    const float* __restrict__ Wl, const float* __restrict__ bl,
    float* __restrict__ out) {
  __shared__ unsigned short sH[4][2][16 * 72];  // 18432 B: h1 (bf16) per wave x tile
  __shared__ float sP[4][16 * 36];              //  9216 B: Wl-products (seq reuse)
  __shared__ float sT[4][2][16 * 12];           //  6144 B: gate-triple scratch
  // total ~33.8 KB -> 2 blocks/CU at (256,2)

  const int tid = threadIdx.x;
  const int lane = tid & 63;
  const int wave = tid >> 6;
  const int m = lane & 15;
  const int q = lane >> 4;
  const int job = blockIdx.x * 4 + wave;
  if (job >= NJOBS) return;  // no barriers anywhere -> safe
  const int tau0 = job * 2;  // this wave's two adjacent tiles

  unsigned short* sHw = (unsigned short*)sH + wave * (2 * 16 * 72);
  float* sPw = (float*)sP + wave * (16 * 36);
  float* sTw = (float*)sT + wave * (2 * 16 * 12);

  // zero K-pad cols 48..63 of both h1 regions (48,49 overwritten below)
  {
    int r0 = lane >> 2, c0 = 48 + (lane & 3) * 4;
    *(unsigned long long*)(sHw + r0 * 72 + c0) = 0ull;
    *(unsigned long long*)(sHw + 16 * 72 + r0 * 72 + c0) = 0ull;
  }
  // zero product cols 20..31 (K-pad of the final MFMA)
#pragma unroll
  for (int i = 0; i < 3; ++i) {
    int idx = lane * 3 + i;
    sPw[(idx / 12) * 36 + 20 + idx % 12] = 0.f;
  }

  // x loads for BOTH tiles issued up front (deepest misses first)
  const float* xr0 = x + (size_t)(tau0 * 16 + m) * 128 + q * 8;
  const float* xr1 = xr0 + 16 * 128;
  v4f xb0[8], xb1[8];
#pragma unroll
  for (int s = 0; s < 4; ++s) {
    xb0[2 * s] = *(const v4f*)(xr0 + 32 * s);
    xb0[2 * s + 1] = *(const v4f*)(xr0 + 32 * s + 4);
  }
#pragma unroll
  for (int s = 0; s < 4; ++s) {
    xb1[2 * s] = *(const v4f*)(xr1 + 32 * s);
    xb1[2 * s + 1] = *(const v4f*)(xr1 + 32 * s + 4);
  }

  const frag8* g1 = (const frag8*)(wsb + OFF_B1H);
  const frag8* g2 = (const frag8*)(wsb + OFF_B2H);

  // stage-0 B frags issued before the cvt VALU
  frag8 ba[10], bb[10];
#pragma unroll
  for (int t = 0; t < 10; ++t) ba[t] = g1[t * 64 + lane];

  // per-lane biases from L2 (packed-col order)
  const float* pb1 = (const float*)(wsb + OFF_PB1);
  const float* pb2 = (const float*)(wsb + OFF_PB2);
  float bias1v[10], bias2v[4];
#pragma unroll
  for (int t = 0; t < 10; ++t) bias1v[t] = pb1[16 * t + m];
#pragma unroll
  for (int t = 0; t < 4; ++t) bias2v[t] = pb2[16 * t + m];

  // A -> bf16 (hi only), both tiles; frees xb registers before the K-loop
  frag8 ah0[4], ah1[4];
#pragma unroll
  for (int s = 0; s < 4; ++s) {
    float av[8];
    *(v4f*)av = xb0[2 * s];
    *(v4f*)(av + 4) = xb0[2 * s + 1];
    ah0[s] = cvt8hi(av);
  }
#pragma unroll
  for (int s = 0; s < 4; ++s) {
    float av[8];
    *(v4f*)av = xb1[2 * s];
    *(v4f*)(av + 4) = xb1[2 * s + 1];
    ah1[s] = cvt8hi(av);
  }

  // ---- GEMM1 for both tiles, shared B, double-buffered stage loads ----
  fragC acc0[10], acc1[10];
#pragma unroll
  for (int t = 0; t < 10; ++t) {
    acc0[t] = (fragC){bias1v[t], bias1v[t], bias1v[t], bias1v[t]};
    acc1[t] = acc0[t];
  }
#pragma unroll
  for (int s = 0; s < 4; ++s) {
    frag8* bc = (s & 1) ? bb : ba;
    frag8* bn = (s & 1) ? ba : bb;
    if (s < 3) {  // next stage's loads ahead of this stage's 20 MFMAs
#pragma unroll
      for (int t = 0; t < 10; ++t) bn[t] = g1[((s + 1) * 10 + t) * 64 + lane];
    }
#pragma unroll
    for (int t = 0; t < 10; ++t)
      acc0[t] = __builtin_amdgcn_mfma_f32_16x16x32_bf16(ah0[s], bc[t], acc0[t], 0, 0, 0);
#pragma unroll
    for (int t = 0; t < 10; ++t)
      acc1[t] = __builtin_amdgcn_mfma_f32_16x16x32_bf16(ah1[s], bc[t], acc1[t], 0, 0, 0);
    // stage fence: caps hoisting at one extra buffer; without it the
    // scheduler lifts everything -> R4/R5's spill storm
    __builtin_amdgcn_sched_barrier(0);
  }

  // B2 frags load here; gate VALU below covers their latency
  frag8 b2f[8];
#pragma unroll
  for (int i = 0; i < 8; ++i) b2f[i] = g2[i * 64 + lane];

  // ---- layer-1 gates, both tiles (independent -> good ILP) ----
#pragma unroll
  for (int tt = 0; tt < 2; ++tt) {
    const fragC* ac = tt ? acc1 : acc0;
    unsigned short* sHt = sHw + tt * (16 * 72);
    float* sTt = sTw + tt * (16 * 12);
#pragma unroll
    for (int b = 0; b < 3; ++b)
#pragma unroll
      for (int r = 0; r < 4; ++r) {
        float I = fsig(ac[3 * b][r]);
        float T = ftanh(ac[3 * b + 1][r]);
        float O = fsig(ac[3 * b + 2][r]);
        sHt[(q * 4 + r) * 72 + 16 * b + m] = f2bf(O * ftanh(I * T));
      }
    if (m < 6) {  // ch 48,49 triples to scratch
#pragma unroll
      for (int r = 0; r < 4; ++r) sTt[(q * 4 + r) * 6 + m] = ac[9][r];
    }
    {
      int row = lane & 15, cc = lane >> 4;
      if (cc < 2) {  // 32 parallel tasks
        float I = fsig(sTt[row * 6 + 3 * cc]);
        float T = ftanh(sTt[row * 6 + 3 * cc + 1]);
        float O = fsig(sTt[row * 6 + 3 * cc + 2]);
        sHt[row * 72 + 48 + cc] = f2bf(O * ftanh(I * T));
      }
    }
  }

  // ---- GEMM2 + epilogue per tile (sP reused; same-wave LDS ordering) ----
  const float wlm = Wl[m];
  const float wlc = Wl[16 + q];
  const float blv = bl[0];
#pragma unroll
  for (int tt = 0; tt < 2; ++tt) {
    unsigned short* sHt = sHw + tt * (16 * 72);
    float* sTt = sTw + tt * (16 * 12);
    frag8 hh[2];
#pragma unroll
    for (int s = 0; s < 2; ++s)
      hh[s] = *(const frag8*)(sHt + m * 72 + 32 * s + 8 * q);
    fragC acc2[4];
#pragma unroll
    for (int t = 0; t < 4; ++t)
      acc2[t] = (fragC){bias2v[t], bias2v[t], bias2v[t], bias2v[t]};
#pragma unroll
    for (int s = 0; s < 2; ++s)
#pragma unroll
      for (int t = 0; t < 4; ++t)
        acc2[t] = __builtin_amdgcn_mfma_f32_16x16x32_bf16(hh[s], b2f[s * 4 + t], acc2[t], 0, 0, 0);

    // layer-2 gates -> relu(h2)*Wl products into sP (f32, pitch 36)
#pragma unroll
    for (int r = 0; r < 4; ++r) {
      float I = fsig(acc2[0][r]);
      float T = ftanh(acc2[1][r]);
      float O = fsig(acc2[2][r]);
      float h2 = O * ftanh(I * T);
      sPw[(q * 4 + r) * 36 + m] = fmaxf(h2, 0.f) * wlm;
    }
    if (m < 12) {  // ch 16..19 triples
#pragma unroll
      for (int r = 0; r < 4; ++r) sTt[(q * 4 + r) * 12 + m] = acc2[3][r];
    }
    {
      int row = lane & 15, cc = lane >> 4;  // 64 parallel tasks
      float I = fsig(sTt[row * 12 + 3 * cc]);
      float T = ftanh(sTt[row * 12 + 3 * cc + 1]);
      float O = fsig(sTt[row * 12 + 3 * cc + 2]);
      float h2 = O * ftanh(I * T);
      sPw[row * 36 + 16 + cc] = fmaxf(h2, 0.f) * wlc;
    }

    // final dot via MFMA vs ones-B: D[row][0] = sum_k prod[row][k]
    float pv[8];
    *(v4f*)pv       = *(const v4f*)(sPw + m * 36 + q * 8);
    *(v4f*)(pv + 4) = *(const v4f*)(sPw + m * 36 + q * 8 + 4);
    frag8 pa, pl;
    cvt8(pv, pa, pl);  // hi/lo split keeps fp32-grade accuracy
    frag8 bw;
#pragma unroll
    for (int j = 0; j < 8; ++j)
      bw[j] = (short)((m == 0 && (8 * q + j) < 20) ? 0x3F80 : 0);
    fragC acco = (fragC){0.f, 0.f, 0.f, 0.f};
    acco = __builtin_amdgcn_mfma_f32_16x16x32_bf16(pa, bw, acco, 0, 0, 0);
    acco = __builtin_amdgcn_mfma_f32_16x16x32_bf16(pl, bw, acco, 0, 0, 0);

    if (m == 0) {  // col 0 on lanes 16q; row = 4q+r
      v4f res;
#pragma unroll
      for (int r = 0; r < 4; ++r) res[r] = acco[r] + blv;
      *(v4f*)(out + (tau0 + tt) * 16 + 4 * q) = res;
    }
  }
}

extern "C" void kernel_launch(void* const* d_in, const int* in_sizes, int n_in,
                              void* d_out, int out_size, void* d_ws, size_t ws_size,
                              hipStream_t stream) {
  (void)in_sizes; (void)n_in; (void)out_size; (void)ws_size;
  const float* x = (const float*)d_in[0];
  // d_in[1] edge_index, d_in[2] edge_weight, d_in[5] theta1, d_in[9] theta2: dead
  const float* Wx1 = (const float*)d_in[3];
  const float* bx1 = (const float*)d_in[4];
  const float* bconv1 = (const float*)d_in[6];
  const float* Wx2 = (const float*)d_in[7];
  const float* bx2 = (const float*)d_in[8];
  const float* bconv2 = (const float*)d_in[10];
  const float* Wl = (const float*)d_in[11];
  const float* bl = (const float*)d_in[12];
  unsigned char* ws = (unsigned char*)d_ws;  // needs ~50 KB

  hipLaunchKernelGGL(pack_weights, dim3(32), dim3(256), 0, stream,
                     Wx1, bx1, bconv1, Wx2, bx2, bconv2, ws);
  hipLaunchKernelGGL(gclstm_main, dim3((NJOBS + 3) / 4), dim3(256), 0, stream,
                     x, ws, Wl, bl, (float*)d_out);
}